// Round 11
// baseline (681.082 us; speedup 1.0000x reference)
//
#include <hip/hip_runtime.h>

// Exphormer attention, fp32 accuracy via split-bf16 MFMA, atomic-free agg.
// Pipeline: memset(cnt+gtotal) -> proj(+hist) -> scan1 -> scatter -> agg.
// CSR regions are dst-DISJOINT but not dst-ordered (off via returning
// atomicAdd of block sums); agg uses j1 = off[d] + cnt[d]. Within-dst edge
// order is scatter-atomic order (fp sum reorder ~1e-5, accepted since R7).

typedef __attribute__((ext_vector_type(8))) short bf16x8;
typedef __attribute__((ext_vector_type(4))) float f32x4;
union frag_u { uint32_t u[4]; uint4 u4; bf16x8 v; };

__device__ __forceinline__ uint32_t pack2(float a, float b) {
    return (__float_as_uint(a) >> 16) | (__float_as_uint(b) & 0xffff0000u);
}
__device__ __forceinline__ void cvt4(float4 v, uint32_t& h0, uint32_t& h1,
                                     uint32_t& l0, uint32_t& l1) {
    float hx = __uint_as_float(__float_as_uint(v.x) & 0xffff0000u);
    float hy = __uint_as_float(__float_as_uint(v.y) & 0xffff0000u);
    float hz = __uint_as_float(__float_as_uint(v.z) & 0xffff0000u);
    float hw = __uint_as_float(__float_as_uint(v.w) & 0xffff0000u);
    h0 = pack2(v.x, v.y);
    h1 = pack2(v.z, v.w);
    l0 = pack2(v.x - hx, v.y - hy);
    l1 = pack2(v.z - hz, v.w - hw);
}

// ---------------- Kernel 1: Q/K/V projection + dst histogram ----------------
// Launched with a SMALL grid (512) so the 50KB/block weight staging is
// amortized over ~6 tile iterations (R10's 3125 blocks re-fetched 156MB).
__global__ __launch_bounds__(256) void proj_kernel(
    const float* __restrict__ x,
    const float* __restrict__ Wq, const float* __restrict__ bq,
    const float* __restrict__ Wk, const float* __restrict__ bk,
    const float* __restrict__ Wv, const float* __restrict__ bv,
    const int* __restrict__ ei, int* __restrict__ cnt,
    float* __restrict__ Qb, float* __restrict__ KV,
    int n, int EG)
{
    __shared__ float WqT[64 * 65];
    __shared__ float WkT[64 * 65];
    __shared__ float WvT[64 * 65];
    __shared__ float xs[4][4][64];

    const int tid  = threadIdx.x;
    const int wave = tid >> 6;
    const int lane = tid & 63;

    #pragma unroll
    for (int k = 0; k < 16; ++k) {
        int idx = tid + k * 256;
        int j = idx >> 6, i = idx & 63;
        WqT[i * 65 + j] = Wq[idx];
        WkT[i * 65 + j] = Wk[idx];
        WvT[i * 65 + j] = Wv[idx];
    }
    const float bqv = bq[lane];
    const float bkv = bk[lane];
    const float bvv = bv[lane];
    __syncthreads();

    for (int blockbase = blockIdx.x * 16; blockbase < n;
         blockbase += gridDim.x * 16) {
        int base = blockbase + wave * 4;
        #pragma unroll
        for (int j = 0; j < 4; ++j) {
            int node = base + j;
            xs[wave][j][lane] = (node < n) ? x[node * 64 + lane] : 0.f;
        }
        __syncthreads();

        float accq[4], acck[4], accv[4];
        #pragma unroll
        for (int j = 0; j < 4; ++j) { accq[j] = bqv; acck[j] = bkv; accv[j] = bvv; }

        #pragma unroll
        for (int f = 0; f < 16; ++f) {
            float wq[4], wk[4], wv[4];
            #pragma unroll
            for (int u = 0; u < 4; ++u) {
                int i = 4 * f + u;
                wq[u] = WqT[i * 65 + lane];
                wk[u] = WkT[i * 65 + lane];
                wv[u] = WvT[i * 65 + lane];
            }
            #pragma unroll
            for (int j = 0; j < 4; ++j) {
                float4 xv = *reinterpret_cast<const float4*>(&xs[wave][j][4 * f]);
                accq[j] = fmaf(xv.x, wq[0], accq[j]);
                accq[j] = fmaf(xv.y, wq[1], accq[j]);
                accq[j] = fmaf(xv.z, wq[2], accq[j]);
                accq[j] = fmaf(xv.w, wq[3], accq[j]);
                acck[j] = fmaf(xv.x, wk[0], acck[j]);
                acck[j] = fmaf(xv.y, wk[1], acck[j]);
                acck[j] = fmaf(xv.z, wk[2], acck[j]);
                acck[j] = fmaf(xv.w, wk[3], acck[j]);
                accv[j] = fmaf(xv.x, wv[0], accv[j]);
                accv[j] = fmaf(xv.y, wv[1], accv[j]);
                accv[j] = fmaf(xv.z, wv[2], accv[j]);
                accv[j] = fmaf(xv.w, wv[3], accv[j]);
            }
        }

        #pragma unroll
        for (int j = 0; j < 4; ++j) {
            int node = base + j;
            if (node < n) {
                Qb[(size_t)node * 64 + lane]       = accq[j];
                KV[(size_t)node * 128 + lane]      = acck[j];
                KV[(size_t)node * 128 + 64 + lane] = accv[j];
            }
        }
        __syncthreads();
    }

    // ---- dst histogram ----
    {
        const int nt4 = EG >> 2;
        int i  = blockIdx.x * blockDim.x + threadIdx.x;
        int st = gridDim.x * blockDim.x;
        const int4* d4 = reinterpret_cast<const int4*>(ei + EG);
        for (int e = i; e < nt4; e += st) {
            int4 d = d4[e];
            atomicAdd(&cnt[d.x], 1);
            atomicAdd(&cnt[d.y], 1);
            atomicAdd(&cnt[d.z], 1);
            atomicAdd(&cnt[d.w], 1);
        }
    }
}

// ---------------- Kernel 2: one-pass region assignment ----------------
// off[i] = (atomic base for this block) + exclusive-prefix within block.
// Regions are disjoint, cover [0,EG), but NOT dst-ordered (valid for agg).
__global__ __launch_bounds__(256) void scan_kernel(
    const int* __restrict__ cnt, int* __restrict__ off,
    int* __restrict__ cursor, int* __restrict__ gtotal, int n)
{
    __shared__ int s[256];
    __shared__ int sbase;
    const int t = threadIdx.x;
    const int i = blockIdx.x * 256 + t;
    const int v = (i < n) ? cnt[i] : 0;
    s[t] = v;
    __syncthreads();
    #pragma unroll
    for (int d = 1; d < 256; d <<= 1) {
        int u = (t >= d) ? s[t - d] : 0;
        __syncthreads();
        s[t] += u;
        __syncthreads();
    }
    if (t == 255) sbase = atomicAdd(gtotal, s[255]);
    __syncthreads();
    if (i < n) {
        int o = sbase + s[t] - v;
        off[i]    = o;
        cursor[i] = o;
    }
}

// ---------------- Kernel 3: scatter {eid, src} into dst regions ----------------
__global__ __launch_bounds__(256) void scatter_kernel(
    const int* __restrict__ ei, int* __restrict__ cursor,
    int2* __restrict__ perm2, int EG)
{
    int i  = blockIdx.x * blockDim.x + threadIdx.x;
    int st = gridDim.x * blockDim.x;
    for (int e = i; e < EG; e += st) {
        int d = ei[EG + e];
        int s = ei[e];
        int p = atomicAdd(&cursor[d], 1);
        perm2[p] = make_int2(e, s);
    }
}

// ---------------- Kernel 4: agg — 4 dsts/wave, MFMA, zero atomics ----------------
// Table batching: one 64-lane perm2 load covers FOUR 16-edge tiles
// (lane = (c=lane>>4, grp=(lane&15)>>2, slot=lane&3)); entries broadcast
// via shfl (no LDS tables, no wave barriers). Next batch prefetched.
// A row m of tile: edge slot (grp=m>>2, slot=m&3); C layout: lane(g,q) owns
// row 4g+r (dst group g, slot r), col 16nt+q (dim). Verified R6/R8/R10.
__global__ __launch_bounds__(256) void agg_kernel(
    const float* __restrict__ ea, const int2* __restrict__ perm2,
    const int* __restrict__ off, const int* __restrict__ cnt,
    const float* __restrict__ Qb, const float* __restrict__ KV,
    const float* __restrict__ We, const float* __restrict__ be,
    float* __restrict__ out, int n)
{
    __shared__ uint4 bfragLDS[16][64];   // We fragments, 16 KB

    const int tid  = threadIdx.x;
    const int wave = __builtin_amdgcn_readfirstlane(tid >> 6);
    const int lane = tid & 63;
    const int g    = lane >> 4;
    const int q    = lane & 15;

    {   // build B fragments: wave w handles nt = w
        const int nt = wave;
        #pragma unroll
        for (int ks = 0; ks < 2; ++ks) {
            frag_u fh, fl;
            #pragma unroll
            for (int b = 0; b < 2; ++b) {
                float4 w4 = *reinterpret_cast<const float4*>(
                    &We[(size_t)(16 * nt + q) * 64 + 32 * ks + 16 * b + 4 * g]);
                cvt4(w4, fh.u[2 * b + 0], fh.u[2 * b + 1],
                         fl.u[2 * b + 0], fl.u[2 * b + 1]);
            }
            bfragLDS[nt * 4 + ks * 2 + 0][lane] = fh.u4;
            bfragLDS[nt * 4 + ks * 2 + 1][lane] = fl.u4;
        }
    }
    float bias4[4];
    #pragma unroll
    for (int nt = 0; nt < 4; ++nt) bias4[nt] = be[16 * nt + q];
    __syncthreads();

    const int nw   = gridDim.x * 4;
    const int nd4  = n >> 2;            // n % 4 == 0
    const int grp  = (lane & 15) >> 2;  // table-load view
    const int slot = lane & 3;
    const int coff = lane >> 4;

    for (int wid = blockIdx.x * 4 + wave; wid < nd4; wid += nw) {
        const int mydst = (wid << 2) + g;
        const int j0  = off[mydst];
        const int cd  = cnt[mydst];

        float qreg[4];
        #pragma unroll
        for (int nt = 0; nt < 4; ++nt)
            qreg[nt] = Qb[(size_t)mydst * 64 + 16 * nt + q];

        const int j0p = __shfl(j0, grp << 4);
        const int j1p = j0p + __shfl(cd, grp << 4);

        int dm = max(cd, __shfl_xor(cd, 16));
        dm = max(dm, __shfl_xor(dm, 32));
        const int iters = __builtin_amdgcn_readfirstlane((dm + 3) >> 2);
        const int nb    = (iters + 3) >> 2;

        float macc[4] = {0.f, 0.f, 0.f, 0.f};

        // prologue: batch 0 table load (lane covers tile coff, entry grp/slot)
        int2 cur = make_int2(0, -1);
        {
            const int pl = j0p + 4 * coff + slot;
            if (pl < j1p) cur = perm2[pl];
        }

        for (int b = 0; b < nb; ++b) {
            // prefetch next batch's table
            int2 nxt = make_int2(0, -1);
            if (b + 1 < nb) {
                const int pn = j0p + 16 * (b + 1) + 4 * coff + slot;
                if (pn < j1p) nxt = perm2[pn];
            }
            const int maxc2 = iters - 4 * b;   // wave-uniform

            #pragma unroll
            for (int c2 = 0; c2 < 4; ++c2) {
                if (c2 < maxc2) {
                    // A fragments: row q -> edge id from table lane (c2,q)
                    const int eidq = __shfl(cur.x, (c2 << 4) | q);
                    const float* arow = ea + (size_t)eidq * 64;
                    frag_u Ah[2], Al[2];
                    #pragma unroll
                    for (int ks = 0; ks < 2; ++ks) {
                        #pragma unroll
                        for (int bb = 0; bb < 2; ++bb) {
                            float4 a4 = *reinterpret_cast<const float4*>(
                                &arow[32 * ks + 16 * bb + 4 * g]);
                            cvt4(a4, Ah[ks].u[2 * bb + 0], Ah[ks].u[2 * bb + 1],
                                     Al[ks].u[2 * bb + 0], Al[ks].u[2 * bb + 1]);
                        }
                    }

                    // Ee = ea @ We^T + be (split-bf16, 24 MFMA)
                    f32x4 acc[4];
                    #pragma unroll
                    for (int nt = 0; nt < 4; ++nt) {
                        acc[nt][0] = bias4[nt]; acc[nt][1] = bias4[nt];
                        acc[nt][2] = bias4[nt]; acc[nt][3] = bias4[nt];
                        #pragma unroll
                        for (int ks = 0; ks < 2; ++ks) {
                            frag_u bh, bl;
                            bh.u4 = bfragLDS[nt * 4 + ks * 2 + 0][lane];
                            bl.u4 = bfragLDS[nt * 4 + ks * 2 + 1][lane];
                            acc[nt] = __builtin_amdgcn_mfma_f32_16x16x32_bf16(
                                          Al[ks].v, bh.v, acc[nt], 0, 0, 0);
                            acc[nt] = __builtin_amdgcn_mfma_f32_16x16x32_bf16(
                                          Ah[ks].v, bl.v, acc[nt], 0, 0, 0);
                            acc[nt] = __builtin_amdgcn_mfma_f32_16x16x32_bf16(
                                          Ah[ks].v, bh.v, acc[nt], 0, 0, 0);
                        }
                    }

                    // score + register accumulate
                    #pragma unroll
                    for (int r = 0; r < 4; ++r) {
                        const int srcr = __shfl(cur.y, (c2 << 4) | (g << 2) | r);
                        const float* kb = KV + (size_t)max(srcr, 0) * 128 + q;
                        #pragma unroll
                        for (int nt = 0; nt < 4; ++nt) {
                            const float kv = kb[16 * nt];
                            const float vv = kb[64 + 16 * nt];
                            float t = kv * qreg[nt] * 0.25f * acc[nt][r];
                            t += __shfl_xor(t, 1);
                            t += __shfl_xor(t, 2);
                            t += __shfl_xor(t, 4);
                            t += __shfl_xor(t, 8);
                            t = fminf(fmaxf(t, -5.f), 5.f);
                            const float s = __expf(t);
                            if (srcr >= 0) macc[nt] = fmaf(vv, s, macc[nt]);
                        }
                    }
                }
            }
            cur = nxt;
        }

        #pragma unroll
        for (int nt = 0; nt < 4; ++nt)
            out[(size_t)mydst * 64 + 16 * nt + q] = macc[nt];
    }
}

extern "C" void kernel_launch(void* const* d_in, const int* in_sizes, int n_in,
                              void* d_out, int out_size, void* d_ws, size_t ws_size,
                              hipStream_t stream) {
    const float* x   = (const float*)d_in[0];
    const float* ea  = (const float*)d_in[1];
    const int*   ei  = (const int*)d_in[2];
    const float* Wq  = (const float*)d_in[3];
    const float* bq  = (const float*)d_in[4];
    const float* Wk  = (const float*)d_in[5];
    const float* bk  = (const float*)d_in[6];
    const float* We  = (const float*)d_in[7];
    const float* be  = (const float*)d_in[8];
    const float* Wv  = (const float*)d_in[9];
    const float* bv  = (const float*)d_in[10];
    float* out = (float*)d_out;

    const int n  = in_sizes[0] / 64;   // 50000
    const int EG = in_sizes[1] / 64;   // 1600000

    // ws: Qb n*64 f | KV n*128 f | cnt n | gtotal 1 | pad 1 | off n | cursor n | perm2 EG int2
    float* Qb    = (float*)d_ws;
    float* KV    = Qb + (size_t)n * 64;
    int*   cnt   = (int*)(KV + (size_t)n * 128);
    int*   gtot  = cnt + n;
    int*   off   = gtot + 2;
    int*   cursor= off + n;
    int2*  perm2 = (int2*)(cursor + n);

    hipMemsetAsync(cnt, 0, (size_t)(n + 1) * sizeof(int), stream);  // cnt + gtotal

    proj_kernel<<<512, 256, 0, stream>>>(x, Wq, bq, Wk, bk, Wv, bv,
                                         ei, cnt, Qb, KV, n, EG);

    const int nbs = (n + 255) / 256;   // 196
    scan_kernel<<<nbs, 256, 0, stream>>>(cnt, off, cursor, gtot, n);

    scatter_kernel<<<2048, 256, 0, stream>>>(ei, cursor, perm2, EG);

    const int aggGrid = (n / 4 + 3) / 4;   // 3125 blocks = 12500 waves
    agg_kernel<<<aggGrid, 256, 0, stream>>>(ea, perm2, off, cnt,
                                            Qb, KV, We, be, out, n);
}

// Round 12
// 498.739 us; speedup vs baseline: 1.3656x; 1.3656x over previous
//
#include <hip/hip_runtime.h>

// Exphormer attention, fp32 accuracy via split-bf16 MFMA, atomic-free agg.
// Pipeline: memset -> proj(+hist) -> scan1 -> scatter{eid,src} -> agg.
// agg: wave owns 4 dsts; 16-edge MFMA tiles; LDS tables (R10-proven),
// double-buffered + software-pipelined; PERMUTED node layout so per-lane
// head values are contiguous (float4 KV/Q loads instead of stride-16).
// Node storage permutation: value for dim d=16*nt+q stored at [4*q+nt].

typedef __attribute__((ext_vector_type(8))) short bf16x8;
typedef __attribute__((ext_vector_type(4))) float f32x4;
union frag_u { uint32_t u[4]; uint4 u4; bf16x8 v; };

__device__ __forceinline__ uint32_t pack2(float a, float b) {
    return (__float_as_uint(a) >> 16) | (__float_as_uint(b) & 0xffff0000u);
}
__device__ __forceinline__ void cvt4(float4 v, uint32_t& h0, uint32_t& h1,
                                     uint32_t& l0, uint32_t& l1) {
    float hx = __uint_as_float(__float_as_uint(v.x) & 0xffff0000u);
    float hy = __uint_as_float(__float_as_uint(v.y) & 0xffff0000u);
    float hz = __uint_as_float(__float_as_uint(v.z) & 0xffff0000u);
    float hw = __uint_as_float(__float_as_uint(v.w) & 0xffff0000u);
    h0 = pack2(v.x, v.y);
    h1 = pack2(v.z, v.w);
    l0 = pack2(v.x - hx, v.y - hy);
    l1 = pack2(v.z - hz, v.w - hw);
}

// ---------------- Kernel 1: Q/K/V projection (permuted write) + dst hist ----
__global__ __launch_bounds__(256) void proj_kernel(
    const float* __restrict__ x,
    const float* __restrict__ Wq, const float* __restrict__ bq,
    const float* __restrict__ Wk, const float* __restrict__ bk,
    const float* __restrict__ Wv, const float* __restrict__ bv,
    const int* __restrict__ ei, int* __restrict__ cnt,
    float* __restrict__ Qb, float* __restrict__ KV,
    int n, int EG)
{
    __shared__ float WqT[64 * 65];
    __shared__ float WkT[64 * 65];
    __shared__ float WvT[64 * 65];
    __shared__ float xs[4][4][64];

    const int tid  = threadIdx.x;
    const int wave = tid >> 6;
    const int lane = tid & 63;
    // permuted offset for dim d=lane: head nt=lane>>4, in-head q=lane&15
    const int pq   = 4 * (lane & 15) + (lane >> 4);

    #pragma unroll
    for (int k = 0; k < 16; ++k) {
        int idx = tid + k * 256;
        int j = idx >> 6, i = idx & 63;
        WqT[i * 65 + j] = Wq[idx];
        WkT[i * 65 + j] = Wk[idx];
        WvT[i * 65 + j] = Wv[idx];
    }
    const float bqv = bq[lane];
    const float bkv = bk[lane];
    const float bvv = bv[lane];
    __syncthreads();

    for (int blockbase = blockIdx.x * 16; blockbase < n;
         blockbase += gridDim.x * 16) {
        int base = blockbase + wave * 4;
        #pragma unroll
        for (int j = 0; j < 4; ++j) {
            int node = base + j;
            xs[wave][j][lane] = (node < n) ? x[node * 64 + lane] : 0.f;
        }
        __syncthreads();

        float accq[4], acck[4], accv[4];
        #pragma unroll
        for (int j = 0; j < 4; ++j) { accq[j] = bqv; acck[j] = bkv; accv[j] = bvv; }

        #pragma unroll
        for (int f = 0; f < 16; ++f) {
            float wq[4], wk[4], wv[4];
            #pragma unroll
            for (int u = 0; u < 4; ++u) {
                int i = 4 * f + u;
                wq[u] = WqT[i * 65 + lane];
                wk[u] = WkT[i * 65 + lane];
                wv[u] = WvT[i * 65 + lane];
            }
            #pragma unroll
            for (int j = 0; j < 4; ++j) {
                float4 xv = *reinterpret_cast<const float4*>(&xs[wave][j][4 * f]);
                accq[j] = fmaf(xv.x, wq[0], accq[j]);
                accq[j] = fmaf(xv.y, wq[1], accq[j]);
                accq[j] = fmaf(xv.z, wq[2], accq[j]);
                accq[j] = fmaf(xv.w, wq[3], accq[j]);
                acck[j] = fmaf(xv.x, wk[0], acck[j]);
                acck[j] = fmaf(xv.y, wk[1], acck[j]);
                acck[j] = fmaf(xv.z, wk[2], acck[j]);
                acck[j] = fmaf(xv.w, wk[3], acck[j]);
                accv[j] = fmaf(xv.x, wv[0], accv[j]);
                accv[j] = fmaf(xv.y, wv[1], accv[j]);
                accv[j] = fmaf(xv.z, wv[2], accv[j]);
                accv[j] = fmaf(xv.w, wv[3], accv[j]);
            }
        }

        #pragma unroll
        for (int j = 0; j < 4; ++j) {
            int node = base + j;
            if (node < n) {
                Qb[(size_t)node * 64 + pq]        = accq[j];
                KV[(size_t)node * 128 + pq]       = acck[j];
                KV[(size_t)node * 128 + 64 + pq]  = accv[j];
            }
        }
        __syncthreads();
    }

    // ---- dst histogram ----
    {
        const int nt4 = EG >> 2;
        int i  = blockIdx.x * blockDim.x + threadIdx.x;
        int st = gridDim.x * blockDim.x;
        const int4* d4 = reinterpret_cast<const int4*>(ei + EG);
        for (int e = i; e < nt4; e += st) {
            int4 d = d4[e];
            atomicAdd(&cnt[d.x], 1);
            atomicAdd(&cnt[d.y], 1);
            atomicAdd(&cnt[d.z], 1);
            atomicAdd(&cnt[d.w], 1);
        }
    }
}

// ---------------- Kernel 2: one-pass region assignment ----------------
__global__ __launch_bounds__(256) void scan_kernel(
    const int* __restrict__ cnt, int* __restrict__ off,
    int* __restrict__ cursor, int* __restrict__ gtotal, int n)
{
    __shared__ int s[256];
    __shared__ int sbase;
    const int t = threadIdx.x;
    const int i = blockIdx.x * 256 + t;
    const int v = (i < n) ? cnt[i] : 0;
    s[t] = v;
    __syncthreads();
    #pragma unroll
    for (int d = 1; d < 256; d <<= 1) {
        int u = (t >= d) ? s[t - d] : 0;
        __syncthreads();
        s[t] += u;
        __syncthreads();
    }
    if (t == 255) sbase = atomicAdd(gtotal, s[255]);
    __syncthreads();
    if (i < n) {
        int o = sbase + s[t] - v;
        off[i]    = o;
        cursor[i] = o;
    }
}

// ---------------- Kernel 3: scatter {eid, src} into dst regions ----------------
__global__ __launch_bounds__(256) void scatter_kernel(
    const int* __restrict__ ei, int* __restrict__ cursor,
    int2* __restrict__ perm2, int EG)
{
    int i  = blockIdx.x * blockDim.x + threadIdx.x;
    int st = gridDim.x * blockDim.x;
    for (int e = i; e < EG; e += st) {
        int d = ei[EG + e];
        int s = ei[e];
        int p = atomicAdd(&cursor[d], 1);
        perm2[p] = make_int2(e, s);
    }
}

// ---------------- Kernel 4: agg — pipelined, float4 gathers, zero atomics ----
// A row m of tile = table entry m (grp=m>>2, slot=m&3); C layout: lane(g,q)
// owns row 4g+r (dst group g, slot r), col dim 16nt+q. Verified R6/R8/R10.
__global__ __launch_bounds__(256) void agg_kernel(
    const float* __restrict__ ea, const int2* __restrict__ perm2,
    const int* __restrict__ off, const int* __restrict__ cnt,
    const float* __restrict__ Qb, const float* __restrict__ KV,
    const float* __restrict__ We, const float* __restrict__ be,
    float* __restrict__ out, int n)
{
    __shared__ uint4 bfragLDS[16][64];   // We fragments, 16 KB
    __shared__ int2  tbl[4][2][16];      // per-wave double-buffered tables

    const int tid  = threadIdx.x;
    const int wave = __builtin_amdgcn_readfirstlane(tid >> 6);
    const int lane = tid & 63;
    const int g    = lane >> 4;
    const int q    = lane & 15;

    {   // build B fragments: wave w handles nt = w
        const int nt = wave;
        #pragma unroll
        for (int ks = 0; ks < 2; ++ks) {
            frag_u fh, fl;
            #pragma unroll
            for (int b = 0; b < 2; ++b) {
                float4 w4 = *reinterpret_cast<const float4*>(
                    &We[(size_t)(16 * nt + q) * 64 + 32 * ks + 16 * b + 4 * g]);
                cvt4(w4, fh.u[2 * b + 0], fh.u[2 * b + 1],
                         fl.u[2 * b + 0], fl.u[2 * b + 1]);
            }
            bfragLDS[nt * 4 + ks * 2 + 0][lane] = fh.u4;
            bfragLDS[nt * 4 + ks * 2 + 1][lane] = fl.u4;
        }
    }
    float bias4[4];
    #pragma unroll
    for (int nt = 0; nt < 4; ++nt) bias4[nt] = be[16 * nt + q];
    __syncthreads();

    const int nw   = gridDim.x * 4;
    const int nd4  = n >> 2;            // n % 4 == 0
    const int slot = lane & 3;          // table-fill view (lanes 0-15)
    const int grpf = (lane & 15) >> 2;

    for (int wid = blockIdx.x * 4 + wave; wid < nd4; wid += nw) {
        const int mydst = (wid << 2) + g;
        const int j0 = off[mydst];
        const int cd = cnt[mydst];

        // permuted layout: one float4 = this lane's 4 per-head Q values
        const f32x4 qv4 = *reinterpret_cast<const f32x4*>(
                              Qb + (size_t)mydst * 64 + 4 * q);

        const int j0f = __shfl(j0, grpf << 4);
        const int j1f = j0f + __shfl(cd, grpf << 4);

        int dm = max(cd, __shfl_xor(cd, 16));
        dm = max(dm, __shfl_xor(dm, 32));
        const int iters = __builtin_amdgcn_readfirstlane((dm + 3) >> 2);

        float macc[4] = {0.f, 0.f, 0.f, 0.f};

        if (iters > 0) {
            // prologue: fill tables for tiles 0 and 1
            if (lane < 16) {
                int p0 = j0f + slot;
                int2 e0 = make_int2(0, -1);
                if (p0 < j1f) e0 = perm2[p0];
                tbl[wave][0][lane] = e0;
                int p1 = j0f + 4 + slot;
                int2 e1 = make_int2(0, -1);
                if (p1 < j1f) e1 = perm2[p1];
                tbl[wave][1][lane] = e1;
            }
            __builtin_amdgcn_wave_barrier();

            // issue tile-0 ea loads
            float4 a4[4];
            {
                const int eid0 = tbl[wave][0][q].x;
                const float* arow = ea + (size_t)eid0 * 64;
                #pragma unroll
                for (int ks = 0; ks < 2; ++ks)
                    #pragma unroll
                    for (int b = 0; b < 2; ++b)
                        a4[ks * 2 + b] = *reinterpret_cast<const float4*>(
                            &arow[32 * ks + 16 * b + 4 * g]);
            }

            for (int c = 0; c < iters; ++c) {
                const int buf = c & 1;

                // 1. current srcs + KV float4 gathers (issue all 8 together)
                int srcs_[4];
                #pragma unroll
                for (int r = 0; r < 4; ++r)
                    srcs_[r] = tbl[wave][buf][4 * g + r].y;
                f32x4 kv4[4], vv4[4];
                #pragma unroll
                for (int r = 0; r < 4; ++r) {
                    const float* kb = KV + (size_t)max(srcs_[r], 0) * 128 + 4 * q;
                    kv4[r] = *reinterpret_cast<const f32x4*>(kb);
                    vv4[r] = *reinterpret_cast<const f32x4*>(kb + 64);
                }

                // 2. next tile ea prefetch (table c+1 filled 2 iters ago)
                float4 a4n[4];
                {
                    const int eidn = tbl[wave][buf ^ 1][q].x;
                    const float* arown = ea + (size_t)eidn * 64;
                    #pragma unroll
                    for (int ks = 0; ks < 2; ++ks)
                        #pragma unroll
                        for (int b = 0; b < 2; ++b)
                            a4n[ks * 2 + b] = *reinterpret_cast<const float4*>(
                                &arown[32 * ks + 16 * b + 4 * g]);
                }

                // 3. table load for tile c+2 (write deferred: T14 split)
                int2 fe = make_int2(0, -1);
                {
                    const int pf = j0f + 4 * (c + 2) + slot;
                    if (lane < 16 && pf < j1f) fe = perm2[pf];
                }

                // 4. cvt current ea -> A frags; MFMA
                frag_u Ah[2], Al[2];
                #pragma unroll
                for (int ks = 0; ks < 2; ++ks)
                    #pragma unroll
                    for (int b = 0; b < 2; ++b)
                        cvt4(a4[ks * 2 + b],
                             Ah[ks].u[2 * b + 0], Ah[ks].u[2 * b + 1],
                             Al[ks].u[2 * b + 0], Al[ks].u[2 * b + 1]);

                f32x4 acc[4];
                #pragma unroll
                for (int nt = 0; nt < 4; ++nt) {
                    acc[nt][0] = bias4[nt]; acc[nt][1] = bias4[nt];
                    acc[nt][2] = bias4[nt]; acc[nt][3] = bias4[nt];
                    #pragma unroll
                    for (int ks = 0; ks < 2; ++ks) {
                        frag_u bh, bl;
                        bh.u4 = bfragLDS[nt * 4 + ks * 2 + 0][lane];
                        bl.u4 = bfragLDS[nt * 4 + ks * 2 + 1][lane];
                        acc[nt] = __builtin_amdgcn_mfma_f32_16x16x32_bf16(
                                      Al[ks].v, bh.v, acc[nt], 0, 0, 0);
                        acc[nt] = __builtin_amdgcn_mfma_f32_16x16x32_bf16(
                                      Ah[ks].v, bl.v, acc[nt], 0, 0, 0);
                        acc[nt] = __builtin_amdgcn_mfma_f32_16x16x32_bf16(
                                      Ah[ks].v, bh.v, acc[nt], 0, 0, 0);
                    }
                }

                // 5. score + register accumulate (consume kv4/vv4)
                #pragma unroll
                for (int r = 0; r < 4; ++r) {
                    #pragma unroll
                    for (int nt = 0; nt < 4; ++nt) {
                        float t = kv4[r][nt] * qv4[nt] * 0.25f * acc[nt][r];
                        t += __shfl_xor(t, 1);
                        t += __shfl_xor(t, 2);
                        t += __shfl_xor(t, 4);
                        t += __shfl_xor(t, 8);
                        t = fminf(fmaxf(t, -5.f), 5.f);
                        const float s = __expf(t);
                        if (srcs_[r] >= 0) macc[nt] = fmaf(vv4[r][nt], s, macc[nt]);
                    }
                }

                // 6. deferred table write (tile c+2 -> buffer c&1)
                if (lane < 16) tbl[wave][buf][lane] = fe;
                __builtin_amdgcn_wave_barrier();

                // 7. rotate ea pipeline
                #pragma unroll
                for (int u = 0; u < 4; ++u) a4[u] = a4n[u];
            }
        }

        #pragma unroll
        for (int nt = 0; nt < 4; ++nt)
            out[(size_t)mydst * 64 + 16 * nt + q] = macc[nt];
    }
}

extern "C" void kernel_launch(void* const* d_in, const int* in_sizes, int n_in,
                              void* d_out, int out_size, void* d_ws, size_t ws_size,
                              hipStream_t stream) {
    const float* x   = (const float*)d_in[0];
    const float* ea  = (const float*)d_in[1];
    const int*   ei  = (const int*)d_in[2];
    const float* Wq  = (const float*)d_in[3];
    const float* bq  = (const float*)d_in[4];
    const float* Wk  = (const float*)d_in[5];
    const float* bk  = (const float*)d_in[6];
    const float* We  = (const float*)d_in[7];
    const float* be  = (const float*)d_in[8];
    const float* Wv  = (const float*)d_in[9];
    const float* bv  = (const float*)d_in[10];
    float* out = (float*)d_out;

    const int n  = in_sizes[0] / 64;   // 50000
    const int EG = in_sizes[1] / 64;   // 1600000

    // ws: Qb n*64 f | KV n*128 f | cnt n | gtot 2 | off n | cursor n | perm2 EG int2
    float* Qb    = (float*)d_ws;
    float* KV    = Qb + (size_t)n * 64;
    int*   cnt   = (int*)(KV + (size_t)n * 128);
    int*   gtot  = cnt + n;
    int*   off   = gtot + 2;
    int*   cursor= off + n;
    int2*  perm2 = (int2*)(cursor + n);

    hipMemsetAsync(cnt, 0, (size_t)(n + 1) * sizeof(int), stream);

    proj_kernel<<<512, 256, 0, stream>>>(x, Wq, bq, Wk, bk, Wv, bv,
                                         ei, cnt, Qb, KV, n, EG);

    const int nbs = (n + 255) / 256;
    scan_kernel<<<nbs, 256, 0, stream>>>(cnt, off, cursor, gtot, n);

    scatter_kernel<<<2048, 256, 0, stream>>>(ei, cursor, perm2, EG);

    const int aggGrid = (n / 4 + 3) / 4;   // 3125 blocks = 12500 waves
    agg_kernel<<<aggGrid, 256, 0, stream>>>(ea, perm2, off, cnt,
                                            Qb, KV, We, be, out, n);
}